// Round 13
// baseline (57.561 us; speedup 1.0000x reference)
//
#include <hip/hip_runtime.h>

// CARAFE: x [4,256,64,64] f32, kernel [4,25,128,128] f32 -> out [4,256,128,128] f32
// out[b,c,2h+p,2w+q] = sum_{ki,kj} x[b,c,h+ki-2,w+kj-2] * kern[b,ki*5+kj,2h+p,2w+q]
//
// R13: packed-FMA probe. Ledger of nulls at ~30us: occupancy (R7/R8), store
// order (R9), LDS->L1 (R10, -25%), LDS amortization 2x (R12). Model: wall =
// sum of half-overlapped pipes (VALU 7.6 + LDS 8 + L1 5 + HBM 12). This round
// halves the biggest VALU term: acc as q-paired float2 -> v_pk_fma_f32 (VOP3P,
// full-rate packed f32 on CDNA4), 800 -> 400 FMA issues/thread. All else = R12:
// 8ch x 2col/thread, 25.6KB weight LDS, v4 stores (R6: NT sub-line = ECC-RMW),
// cc-fast XCD chunking, aligned-v2 x windows, block-uniform edge-row skip.

typedef float v2 __attribute__((ext_vector_type(2)));
typedef float v4 __attribute__((ext_vector_type(4)));

__global__ __launch_bounds__(256, 4)
void carafe_kernel(const float* __restrict__ x,
                   const float* __restrict__ kern,
                   float* __restrict__ out) {
    __shared__ __align__(16) float wt[25 * 256];   // [k][p][ow] for rows {2h,2h+1}

    // XCD-chunked swizzle: 1024 blocks, 128 per XCD (cc fast within a chunk).
    const int raw = blockIdx.x;
    const int l   = (raw & 7) * 128 + (raw >> 3);
    const int cc  = l & 3;           // 64-channel chunk
    const int h   = (l >> 2) & 63;   // input row
    const int b   = l >> 8;          // batch
    const int tid = threadIdx.x;
    const int t   = tid & 31;        // col group: input cols 2t,2t+1 -> out 4t..4t+3
    const int g   = tid >> 5;        // ch group: 8 channels
    const int c0  = cc * 64 + g * 8;

    // ---- stage weights (25.6KB) as v4: 1600 v4 loads, coalesced ----
    {
        const float* kbase = kern + (size_t)b * 25 * 16384 + (size_t)(2 * h) * 128;
        for (int idx = tid; idx < 1600; idx += 256) {
            const int f = idx * 4;           // flat float index in wt
            const int k = f >> 8;
            const int r = f & 255;           // p*128 + ow
            *(v4*)&wt[f] = *(const v4*)(kbase + (size_t)k * 16384 + r);
        }
    }
    __syncthreads();

    v2 acc[8][2][2] = {};            // [ch][cj][p], q packed in the v2 lanes
    const float* xb = x + (size_t)(b * 256 + c0) * 4096;

#pragma unroll
    for (int ki = 0; ki < 5; ++ki) {
        const int gr = h + ki - 2;
        if ((unsigned)gr >= 64u) continue;     // block-uniform zero-pad rows

        // x window per ch: cols 2t-2 .. 2t+3 via 3 aligned v2 loads
        float xw[8][6];
#pragma unroll
        for (int ch = 0; ch < 8; ++ch) {
            const float* rowp = xb + (size_t)ch * 4096 + gr * 64;
            const v2 A = *(const v2*)(rowp + (t ? 2 * t - 2 : 0));
            const v2 B = *(const v2*)(rowp + 2 * t);
            const v2 C = *(const v2*)(rowp + (t < 31 ? 2 * t + 2 : 60));
            xw[ch][0] = t ? A.x : 0.0f;            // col 2t-2
            xw[ch][1] = t ? A.y : 0.0f;            // col 2t-1
            xw[ch][2] = B.x;  xw[ch][3] = B.y;     // cols 2t, 2t+1
            xw[ch][4] = (t < 31) ? C.x : 0.0f;     // col 2t+2
            xw[ch][5] = (t < 31) ? C.y : 0.0f;     // col 2t+3
        }

#pragma unroll
        for (int kj = 0; kj < 5; ++kj) {
            const int k = ki * 5 + kj;
            // q-pair views of the weight rows: w0q[cj] = weights for (p=0, q=0/1)
            const v2* w0q = (const v2*)&wt[k * 256 + 4 * t];        // p=0
            const v2* w1q = (const v2*)&wt[k * 256 + 128 + 4 * t];  // p=1
            const v2 wq00 = w0q[0], wq01 = w0q[1];
            const v2 wq10 = w1q[0], wq11 = w1q[1];
#pragma unroll
            for (int ch = 0; ch < 8; ++ch) {
#pragma unroll
                for (int cj = 0; cj < 2; ++cj) {
                    const float xv = xw[ch][cj + kj];
                    const v2 xvv = { xv, xv };
                    acc[ch][cj][0] += (cj ? wq01 : wq00) * xvv;   // v_pk_fma_f32
                    acc[ch][cj][1] += (cj ? wq11 : wq10) * xvv;
                }
            }
        }
    }

    // ---- stores: 1 v4 per (ch,p); lanes t=0..31 cover a contiguous 512B row ----
#pragma unroll
    for (int ch = 0; ch < 8; ++ch) {
        float* ob = out + ((size_t)(b * 256 + c0 + ch) * 128 + 2 * h) * 128 + 4 * t;
#pragma unroll
        for (int p = 0; p < 2; ++p) {
            v4 s;
            s.x = acc[ch][0][p].x; s.y = acc[ch][0][p].y;
            s.z = acc[ch][1][p].x; s.w = acc[ch][1][p].y;
            *(v4*)(ob + p * 128) = s;
        }
    }
}

extern "C" void kernel_launch(void* const* d_in, const int* in_sizes, int n_in,
                              void* d_out, int out_size, void* d_ws, size_t ws_size,
                              hipStream_t stream) {
    const float* x    = (const float*)d_in[0];
    const float* kern = (const float*)d_in[1];
    float* out        = (float*)d_out;
    // grid: b(4) * h(64) * cc(4) = 1024 blocks of 256 threads
    carafe_kernel<<<dim3(1024), dim3(256), 0, stream>>>(x, kern, out);
}